// Round 12
// baseline (111.964 us; speedup 1.0000x reference)
//
#include <hip/hip_runtime.h>
#include <hip/hip_bf16.h>
#include <math.h>

#define NB 2
#define CIN 256
#define NPOS 4096          // 64*64
#define HID 128
#define NHEAD 4
#define DHEAD 32
#define NBH 8
#define NSPLIT 4
#define QSCALE 0.2550348676144781f   // 32^-0.5 * log2(e), applied in qkv epilogue

typedef __bf16 bf16;
typedef __attribute__((ext_vector_type(8))) __bf16 bf16x8;
typedef __attribute__((ext_vector_type(4))) __bf16 bf16x4;
typedef __attribute__((ext_vector_type(4))) float f32x4;

union B8 { bf16x8 v; bf16x4 h[2]; };

// ws layout (byte offsets), total 14,680,064 B (R17: prep/xt/wb/wob eliminated):
#define QB_OFF  0u            // qb  bf16 [8][4096][32]     2 MB
#define KB_OFF  2097152u      // kb  bf16 [8][4096][32]     2 MB
#define VT_OFF  4194304u      // vtb bf16 [8][32][4096]     2 MB  (V transposed, j-PERMUTED per 64-block)
#define LP_OFF  6291456u      // lp  f32  [4][8][4096]      512 KB
#define AOP_OFF 6815744u      // aop bf16 [4][2][4096][128] 8 MB

// ---------------- Kernel 1: qkv GEMM — x read once, f32 weights direct, vtb j-permuted ----------------
// R17: prep deleted. R10's proven x-direct structure (one block per 32-i-tile x b =
// 256 blocks x 512 thr; block stages its full 32x256 f32 x-tile once -> 8 MB total
// x traffic; computes ALL 384 outputs; W streams f32 from L2 with inline cvt;
// QSCALE in epilogue) + R16's vtb j-permutation so fattn's PV B-operand equals QK's
// C/D register layout. 32-row tiles: global n ng = ((i0>>4)&2)|n, block base i0&~63.
__global__ __launch_bounds__(512) void qkv_kernel(const float* __restrict__ x,
                                                  const float* __restrict__ wqkv,
                                                  bf16* __restrict__ qb,
                                                  bf16* __restrict__ kb,
                                                  bf16* __restrict__ vtb) {
    const int i0 = blockIdx.x * 32;
    const int b  = blockIdx.y;
    const int t  = threadIdx.x;
    const int w  = t >> 6;          // 0..7
    const int lane = t & 63;
    const int quad = lane >> 4;
    const int li   = lane & 15;

    __shared__ bf16 Bs[32][260];    // [i_loc][k]; stride 260 elem = 130 banks == 2 mod 32

    // ---- stage x-tile: 32 i x 256 c, coalesced float4 along i ----
    {
        const int il = (t & 7) * 4;           // i chunk of 4
        #pragma unroll
        for (int u = 0; u < 4; ++u) {
            const int c = (t >> 3) + u * 64;  // 0..255
            float4 v = *(const float4*)(x + ((size_t)b * CIN + c) * NPOS + i0 + il);
            Bs[il    ][c] = (bf16)v.x;
            Bs[il + 1][c] = (bf16)v.y;
            Bs[il + 2][c] = (bf16)v.z;
            Bs[il + 3][c] = (bf16)v.w;
        }
    }
    __syncthreads();

    f32x4 acc[2][3];
    #pragma unroll
    for (int n = 0; n < 2; ++n)
        #pragma unroll
        for (int m = 0; m < 3; ++m) acc[n][m] = (f32x4){0.f,0.f,0.f,0.f};

    #pragma unroll
    for (int k0 = 0; k0 < CIN; k0 += 32) {
        B8 bfr[2];
        #pragma unroll
        for (int n = 0; n < 2; ++n) {
            bfr[n].h[0] = *(const bf16x4*)&Bs[n * 16 + li][k0 + quad * 8];
            bfr[n].h[1] = *(const bf16x4*)&Bs[n * 16 + li][k0 + quad * 8 + 4];
        }
        #pragma unroll
        for (int m = 0; m < 3; ++m) {
            const int orow = w * 48 + m * 16 + li;
            const float* wa = wqkv + (size_t)orow * CIN + k0 + quad * 8;
            float4 a0 = *(const float4*)wa;
            float4 a1 = *(const float4*)(wa + 4);
            B8 af;
            #pragma unroll
            for (int j = 0; j < 4; ++j) { af.v[j] = (bf16)(&a0.x)[j]; af.v[4 + j] = (bf16)(&a1.x)[j]; }
            #pragma unroll
            for (int n = 0; n < 2; ++n)
                acc[n][m] = __builtin_amdgcn_mfma_f32_16x16x32_bf16(af.v, bfr[n].v, acc[n][m], 0, 0, 0);
        }
    }

    #pragma unroll
    for (int m = 0; m < 3; ++m) {
        const int obase = w * 48 + m * 16;
        const int sect  = obase >> 7;            // 0=q 1=k 2=v
        const int oo    = obase & 127;
        const int h     = oo >> 5;
        const int dbase = (oo & 31) + quad * 4;
        const int bh    = b * NHEAD + h;
        #pragma unroll
        for (int n = 0; n < 2; ++n) {
            int i = i0 + n * 16 + li;
            f32x4 v = acc[n][m];
            if (sect == 0) {
                #pragma unroll
                for (int r = 0; r < 4; ++r) v[r] *= QSCALE;
            }
            if (sect <= 1) {
                bf16x4 pk;
                #pragma unroll
                for (int r = 0; r < 4; ++r) pk[r] = (bf16)v[r];
                bf16* base = (sect == 0) ? qb : kb;
                *(bf16x4*)(base + ((size_t)bh * NPOS + i) * DHEAD + dbase) = pk;
            } else {
                // j-permuted V column within the 64-block: ng = global n (0..3)
                const int ng = ((i0 >> 4) & 2) | n;
                const int ip = (i0 & ~63) + ((ng >> 1) << 5) + ((li >> 2) << 3)
                             + ((ng & 1) << 2) + (li & 3);
                #pragma unroll
                for (int r = 0; r < 4; ++r)
                    vtb[((size_t)bh * DHEAD + dbase + r) * NPOS + ip] = (bf16)v[r];
            }
        }
    }
}

// ---------------- Kernel 2: MFMA flash attention — P stays in registers (R16 verbatim) ----------------
__global__ __launch_bounds__(256, 4) void fattn_kernel(const bf16* __restrict__ qb,
                                                       const bf16* __restrict__ kb,
                                                       const bf16* __restrict__ vtb,
                                                       bf16* __restrict__ aop,
                                                       float* __restrict__ lpart) {
    const int id    = blockIdx.x;
    const int g     = id & 31;
    const int iblk  = id >> 5;           // 0..31
    const int bh    = g >> 2;
    const int split = g & 3;
    const int w     = threadIdx.x >> 6;
    const int lane  = threadIdx.x & 63;
    const int quad  = lane >> 4;
    const int li    = lane & 15;
    const int i0    = iblk * 128 + w * 32;
    const int j_lo  = split * 1024;

    const bf16* qrow = qb + (size_t)bh * NPOS * DHEAD;
    const bf16x8 qf0 = *(const bf16x8*)(qrow + (size_t)(i0 + li) * DHEAD + quad * 8);
    const bf16x8 qf1 = *(const bf16x8*)(qrow + (size_t)(i0 + 16 + li) * DHEAD + quad * 8);
    const bf16* kbase  = kb  + (size_t)bh * NPOS * DHEAD;
    const bf16* vtbase = vtb + (size_t)bh * DHEAD * NPOS;

    bf16x8 ones;
    #pragma unroll
    for (int j = 0; j < 8; ++j) ones[j] = (bf16)1.0f;

    f32x4 o00 = {0.f,0.f,0.f,0.f}, o01 = {0.f,0.f,0.f,0.f};
    f32x4 o10 = {0.f,0.f,0.f,0.f}, o11 = {0.f,0.f,0.f,0.f};
    f32x4 l0  = {0.f,0.f,0.f,0.f}, l1  = {0.f,0.f,0.f,0.f};

    __shared__ alignas(16) bf16 Kbuf[2][64][32];   // [buf][j_loc][d], 8 KB
    __shared__ alignas(16) bf16 Vbuf[2][32][64];   // [buf][d][k_slot], 8 KB (slot-swizzled)

    const f32x4 zero = {0.f,0.f,0.f,0.f};

    // staging geometry: each wave stages 16 K-rows (1 KB) + 8 V-rows (1 KB)
    const int krow = w * 16 + (lane >> 2);        // 0..63 (j within tile)
    const int kcol = (lane & 3) * 8;              // d chunk (16 B)
    const int vrow = w * 8 + (lane >> 3);         // 0..31 (d)
    const int vchk = lane & 7;                    // k chunk (16 B)
    const int vslot = vchk ^ (vrow & 7);          // swizzled LDS slot
    const bf16* ksrc = kbase + (size_t)krow * DHEAD + kcol;
    const bf16* vsrc = vtbase + (size_t)vrow * NPOS + vchk * 8;

    bf16x8 kg, vg;

    // prologue: stage tile 0 into buf 0
    kg = *(const bf16x8*)(ksrc + (size_t)j_lo * DHEAD);
    vg = *(const bf16x8*)(vsrc + j_lo);
    *(bf16x8*)&Kbuf[0][krow][kcol]      = kg;
    *(bf16x8*)&Vbuf[0][vrow][vslot * 8] = vg;
    __syncthreads();

    for (int it = 0; it < 16; ++it) {
        const int cur = it & 1;
        const int j0  = j_lo + it * 64;
        // issue next tile's global loads (drain under this iteration's compute)
        if (it < 15) {
            kg = *(const bf16x8*)(ksrc + (size_t)(j0 + 64) * DHEAD);
            vg = *(const bf16x8*)(vsrc + j0 + 64);
        }
        // QK from Kbuf[cur]
        bf16x8 kf[4];
        #pragma unroll
        for (int tt = 0; tt < 4; ++tt)
            kf[tt] = *(const bf16x8*)&Kbuf[cur][16 * tt + li][quad * 8];
        f32x4 s0[4], s1[4];
        #pragma unroll
        for (int tt = 0; tt < 4; ++tt) {
            s0[tt] = __builtin_amdgcn_mfma_f32_16x16x32_bf16(kf[tt], qf0, zero, 0, 0, 0);
            s1[tt] = __builtin_amdgcn_mfma_f32_16x16x32_bf16(kf[tt], qf1, zero, 0, 0, 0);
        }
        // exp in-register -> PV B-fragments directly (k(m) permutation pre-applied to V)
        #pragma unroll
        for (int h2 = 0; h2 < 2; ++h2) {
            B8 pa0, pa1;
            #pragma unroll
            for (int r = 0; r < 4; ++r) {
                pa0.v[r]     = (bf16)__builtin_amdgcn_exp2f(s0[2 * h2][r]);
                pa0.v[4 + r] = (bf16)__builtin_amdgcn_exp2f(s0[2 * h2 + 1][r]);
                pa1.v[r]     = (bf16)__builtin_amdgcn_exp2f(s1[2 * h2][r]);
                pa1.v[4 + r] = (bf16)__builtin_amdgcn_exp2f(s1[2 * h2 + 1][r]);
            }
            const int s0s = (h2 * 4 + quad) ^ (li & 7);   // read swizzle matches write
            bf16x8 v0f = *(const bf16x8*)&Vbuf[cur][li][s0s * 8];
            bf16x8 v1f = *(const bf16x8*)&Vbuf[cur][16 + li][s0s * 8];
            l0  = __builtin_amdgcn_mfma_f32_16x16x32_bf16(ones, pa0.v, l0,  0, 0, 0);
            l1  = __builtin_amdgcn_mfma_f32_16x16x32_bf16(ones, pa1.v, l1,  0, 0, 0);
            o00 = __builtin_amdgcn_mfma_f32_16x16x32_bf16(v0f,  pa0.v, o00, 0, 0, 0);
            o01 = __builtin_amdgcn_mfma_f32_16x16x32_bf16(v1f,  pa0.v, o01, 0, 0, 0);
            o10 = __builtin_amdgcn_mfma_f32_16x16x32_bf16(v0f,  pa1.v, o10, 0, 0, 0);
            o11 = __builtin_amdgcn_mfma_f32_16x16x32_bf16(v1f,  pa1.v, o11, 0, 0, 0);
        }
        // stage next tile into the other buffer (its readers are past the barrier)
        if (it < 15) {
            *(bf16x8*)&Kbuf[cur ^ 1][krow][kcol]      = kg;
            *(bf16x8*)&Vbuf[cur ^ 1][vrow][vslot * 8] = vg;
        }
        __syncthreads();
    }

    const int b = bh >> 2, h = bh & 3;
    {
        const int i = i0 + li;
        bf16* dst = aop + (((size_t)(split * NB + b) * NPOS + i) * HID) + h * DHEAD;
        bf16x4 pk0, pk1;
        #pragma unroll
        for (int r = 0; r < 4; ++r) { pk0[r] = (bf16)o00[r]; pk1[r] = (bf16)o01[r]; }
        *(bf16x4*)(dst + quad * 4)      = pk0;
        *(bf16x4*)(dst + 16 + quad * 4) = pk1;
        if (quad == 0) lpart[((size_t)split * NBH + bh) * NPOS + i] = l0[0];
    }
    {
        const int i = i0 + 16 + li;
        bf16* dst = aop + (((size_t)(split * NB + b) * NPOS + i) * HID) + h * DHEAD;
        bf16x4 pk0, pk1;
        #pragma unroll
        for (int r = 0; r < 4; ++r) { pk0[r] = (bf16)o10[r]; pk1[r] = (bf16)o11[r]; }
        *(bf16x4*)(dst + quad * 4)      = pk0;
        *(bf16x4*)(dst + 16 + quad * 4) = pk1;
        if (quad == 0) lpart[((size_t)split * NBH + bh) * NPOS + i] = l1[0];
    }
}

// ---------------- Kernel 3: proj GEMM — combine once per row, f32 weights direct ----------------
// R17: R15's structure; W-frags cvt'd inline from f32 wout (pattern proven R9/R10).
__global__ __launch_bounds__(256) void proj_kernel(const bf16* __restrict__ aop,
                                                   const float* __restrict__ lpart,
                                                   const float* __restrict__ wout,
                                                   const float* __restrict__ bout,
                                                   float* __restrict__ y) {
    const int i0 = blockIdx.x * 16;
    const int b  = blockIdx.y;
    const int t  = threadIdx.x;
    const int w  = t >> 6;
    const int lane = t & 63;
    const int quad = lane >> 4;
    const int li   = lane & 15;

    __shared__ bf16 Bs[16][132];   // [i_loc][c], 4.2 KB

    // staging with combine: thread = (row, 8-channel chunk); each row combined ONCE
    {
        const int row = t >> 4;          // 0..15
        const int cp  = (t & 15) * 8;    // 0..120
        const int gi  = i0 + row;
        const int h   = cp >> 5;

        float lsum = 0.f;
        #pragma unroll
        for (int s = 0; s < NSPLIT; ++s)
            lsum += lpart[((size_t)s * NBH + b * NHEAD + h) * NPOS + gi];
        const float invl = __builtin_amdgcn_rcpf(lsum);

        float vals[8];
        #pragma unroll
        for (int j = 0; j < 8; ++j) vals[j] = 0.f;
        #pragma unroll
        for (int s = 0; s < NSPLIT; ++s) {
            bf16x8 u = *(const bf16x8*)(aop + (((size_t)(s * NB + b) * NPOS + gi) * HID) + cp);
            #pragma unroll
            for (int j = 0; j < 8; ++j) vals[j] += (float)u[j];
        }
        B8 pk;
        #pragma unroll
        for (int j = 0; j < 8; ++j) pk.v[j] = (bf16)(vals[j] * invl);
        *(bf16x4*)&Bs[row][cp]     = pk.h[0];
        *(bf16x4*)&Bs[row][cp + 4] = pk.h[1];
    }
    __syncthreads();

    f32x4 acc[4];
    #pragma unroll
    for (int m = 0; m < 4; ++m) acc[m] = (f32x4){0.f, 0.f, 0.f, 0.f};

    #pragma unroll
    for (int k0 = 0; k0 < HID; k0 += 32) {
        B8 bf;
        bf.h[0] = *(const bf16x4*)&Bs[li][k0 + quad * 8];
        bf.h[1] = *(const bf16x4*)&Bs[li][k0 + quad * 8 + 4];
        #pragma unroll
        for (int m = 0; m < 4; ++m) {
            const float* wa = wout + (size_t)(w * 64 + m * 16 + li) * HID + k0 + quad * 8;
            float4 a0 = *(const float4*)wa;
            float4 a1 = *(const float4*)(wa + 4);
            B8 af;
            #pragma unroll
            for (int j = 0; j < 4; ++j) { af.v[j] = (bf16)(&a0.x)[j]; af.v[4 + j] = (bf16)(&a1.x)[j]; }
            acc[m] = __builtin_amdgcn_mfma_f32_16x16x32_bf16(af.v, bf.v, acc[m], 0, 0, 0);
        }
    }

    float* yb = y + (size_t)b * CIN * NPOS;
    #pragma unroll
    for (int m = 0; m < 4; ++m) {
        const int oc = w * 64 + m * 16 + quad * 4;
        #pragma unroll
        for (int r = 0; r < 4; ++r)
            yb[(size_t)(oc + r) * NPOS + i0 + li] = acc[m][r] + bout[oc + r];
    }
}

extern "C" void kernel_launch(void* const* d_in, const int* in_sizes, int n_in,
                              void* d_out, int out_size, void* d_ws, size_t ws_size,
                              hipStream_t stream) {
    const float* x    = (const float*)d_in[0];
    const float* wqkv = (const float*)d_in[1];
    const float* wout = (const float*)d_in[2];
    const float* bout = (const float*)d_in[3];
    float* y = (float*)d_out;
    char* ws = (char*)d_ws;

    bf16*  qb  = (bf16*)(ws + QB_OFF);
    bf16*  kb  = (bf16*)(ws + KB_OFF);
    bf16*  vtb = (bf16*)(ws + VT_OFF);
    float* lp  = (float*)(ws + LP_OFF);
    bf16*  aop = (bf16*)(ws + AOP_OFF);

    qkv_kernel<<<dim3(128, 2), 512, 0, stream>>>(x, wqkv, qb, kb, vtb);
    fattn_kernel<<<dim3(1024), 256, 0, stream>>>(qb, kb, vtb, aop, lp);
    proj_kernel<<<dim3(256, 2), 256, 0, stream>>>(aop, lp, wout, bout, y);
}

// Round 13
// 102.868 us; speedup vs baseline: 1.0884x; 1.0884x over previous
//
#include <hip/hip_runtime.h>
#include <hip/hip_bf16.h>
#include <math.h>

#define NB 2
#define CIN 256
#define NPOS 4096          // 64*64
#define HID 128
#define NHEAD 4
#define DHEAD 32
#define NBH 8
#define NSPLIT 4
#define QSCALE 0.2550348676144781f   // 32^-0.5 * log2(e), folded into W_q

typedef __bf16 bf16;
typedef __attribute__((ext_vector_type(8))) __bf16 bf16x8;
typedef __attribute__((ext_vector_type(4))) __bf16 bf16x4;
typedef __attribute__((ext_vector_type(4))) float f32x4;

union B8 { bf16x8 v; bf16x4 h[2]; };

// ws layout (byte offsets), total 19,660,800 B (R0/R11 layout):
#define XT_OFF  0u            // xt  bf16 [2][4096][256]   4 MB
#define QB_OFF  4194304u      // qb  bf16 [8][4096][32]    2 MB  (W_q pre-scaled by QSCALE)
#define KB_OFF  6291456u      // kb  bf16 [8][4096][32]    2 MB
#define VT_OFF  8388608u      // vtb bf16 [8][32][4096]    2 MB  (V transposed, j-PERMUTED per 64-block)
#define AOP_OFF 10485760u     // aop bf16 [4][2][4096][128] 8 MB (partial O, [split][b][i][c])
#define LP_OFF  18874368u     // lp  f32  [4][8][4096]     512 KB
#define WB_OFF  19398656u     // wb  bf16 [384][256]       192 KB
#define WOB_OFF 19595264u     // wob bf16 [256][128]       64 KB

// ---------------- Kernel 0: prep — transpose x to bf16 [b][i][c]; cast weights ----------------
__global__ __launch_bounds__(256) void prep_kernel(const float* __restrict__ x,
                                                   const float* __restrict__ wqkv,
                                                   const float* __restrict__ wout,
                                                   bf16* __restrict__ xt,
                                                   bf16* __restrict__ wb,
                                                   bf16* __restrict__ wob) {
    const int t = threadIdx.x;
    if (blockIdx.y == 4) {
        int tid = blockIdx.x * 256 + t;           // 0..16383
        if (blockIdx.z == 0) {
            #pragma unroll
            for (int u = 0; u < 6; ++u) {
                int idx = tid * 6 + u;            // 98304 = 384*256 exactly
                float v = wqkv[idx];
                if (idx < 32768) v *= QSCALE;     // rows 0..127 = W_q
                wb[idx] = (bf16)v;
            }
        } else {
            wob[tid * 2]     = (bf16)wout[tid * 2];     // 32768 = 256*128
            wob[tid * 2 + 1] = (bf16)wout[tid * 2 + 1];
        }
        return;
    }
    const int b  = blockIdx.z;
    const int c0 = blockIdx.y * 64;
    const int i0 = blockIdx.x * 64;
    __shared__ float Ts[64][65];
    const float* xb = x + (size_t)b * CIN * NPOS;
    #pragma unroll
    for (int u = 0; u < 4; ++u) {
        int c = (t >> 4) + u * 16;
        int i = (t & 15) * 4;
        float4 v = *(const float4*)(xb + (size_t)(c0 + c) * NPOS + i0 + i);
        Ts[c][i] = v.x; Ts[c][i + 1] = v.y; Ts[c][i + 2] = v.z; Ts[c][i + 3] = v.w;
    }
    __syncthreads();
    int i  = t & 63;
    int cc = (t >> 6) * 16;
    B8 o0, o1;
    #pragma unroll
    for (int j = 0; j < 8; ++j) {
        o0.v[j] = (bf16)Ts[cc + j][i];
        o1.v[j] = (bf16)Ts[cc + 8 + j][i];
    }
    bf16* dst = xt + ((size_t)b * NPOS + i0 + i) * CIN + c0 + cc;
    *(bf16x8*)dst       = o0.v;
    *(bf16x8*)(dst + 8) = o1.v;
}

// ---------------- Kernel 1: qkv MFMA GEMM — vtb written j-PERMUTED ----------------
// vtb columns remapped within each 64-block by k(m) = 32*(n>>1) + 8*(li>>2)
// + 4*(n&1) + (li&3)  (m = n*16+li), making fattn's PV B-operand layout equal
// QK's C/D register layout (j is a reduction axis: permuting j is legal iff V is
// permuted identically) — eliminates fattn's plds P round-trip.
__global__ __launch_bounds__(256) void qkv_kernel(const bf16* __restrict__ xt,
                                                  const bf16* __restrict__ wb,
                                                  bf16* __restrict__ qb,
                                                  bf16* __restrict__ kb,
                                                  bf16* __restrict__ vtb) {
    const int i0 = blockIdx.x * 64;
    const int ot = blockIdx.y * 64;
    const int b  = blockIdx.z;
    const int t  = threadIdx.x;
    const int w  = t >> 6;
    const int lane = t & 63;
    const int quad = lane >> 4;
    const int li   = lane & 15;

    __shared__ bf16 Bs[64][36];   // [i_loc][k]

    f32x4 acc[4];
    #pragma unroll
    for (int n = 0; n < 4; ++n) acc[n] = (f32x4){0.f, 0.f, 0.f, 0.f};

    const bf16* xrow = xt + ((size_t)b * NPOS + i0) * CIN;
    const int si = t >> 2;            // 0..63
    const int sk = (t & 3) * 8;       // 0,8,16,24

    for (int k0 = 0; k0 < CIN; k0 += 32) {
        __syncthreads();
        B8 g0;
        g0.v = *(const bf16x8*)(xrow + (size_t)si * CIN + k0 + sk);
        *(bf16x4*)&Bs[si][sk]     = g0.h[0];
        *(bf16x4*)&Bs[si][sk + 4] = g0.h[1];
        __syncthreads();
        bf16x8 afrag = *(const bf16x8*)(wb + (size_t)(ot + w * 16 + li) * CIN + k0 + quad * 8);
        #pragma unroll
        for (int n = 0; n < 4; ++n) {
            B8 bf;
            bf.h[0] = *(const bf16x4*)&Bs[n * 16 + li][quad * 8];
            bf.h[1] = *(const bf16x4*)&Bs[n * 16 + li][quad * 8 + 4];
            acc[n] = __builtin_amdgcn_mfma_f32_16x16x32_bf16(afrag, bf.v, acc[n], 0, 0, 0);
        }
    }

    const int obase = ot + w * 16;
    const int sect  = obase >> 7;            // 0=q 1=k 2=v
    const int oo    = obase & 127;
    const int h     = oo >> 5;
    const int dbase = (oo & 31) + quad * 4;
    const int bh    = b * NHEAD + h;

    #pragma unroll
    for (int n = 0; n < 4; ++n) {
        int i = i0 + n * 16 + li;
        f32x4 v = acc[n];
        if (sect <= 1) {
            bf16x4 pk;
            #pragma unroll
            for (int r = 0; r < 4; ++r) pk[r] = (bf16)v[r];
            bf16* base = (sect == 0) ? qb : kb;
            *(bf16x4*)(base + ((size_t)bh * NPOS + i) * DHEAD + dbase) = pk;
        } else {
            // j-permuted V column: i0 + k(m), m = n*16 + li
            const int ip = i0 + ((n >> 1) << 5) + ((li >> 2) << 3) + ((n & 1) << 2) + (li & 3);
            #pragma unroll
            for (int r = 0; r < 4; ++r)
                vtb[((size_t)bh * DHEAD + dbase + r) * NPOS + ip] = (bf16)v[r];
        }
    }
}

// ---------------- Kernel 2: MFMA flash attention — P stays in registers ----------------
// Cooperative double-buffered K/V LDS staging (4x VMEM dedup); with the vtb
// j-permutation, QK's C/D output IS PV's B-operand: pf_h2 =
// pack(exp(s[2h2][0..3]), exp(s[2h2+1][0..3])) straight from registers.
// 10 DS ops/wave/iter, LDS 16 KB.
__global__ __launch_bounds__(256, 4) void fattn_kernel(const bf16* __restrict__ qb,
                                                       const bf16* __restrict__ kb,
                                                       const bf16* __restrict__ vtb,
                                                       bf16* __restrict__ aop,
                                                       float* __restrict__ lpart) {
    const int id    = blockIdx.x;
    const int g     = id & 31;
    const int iblk  = id >> 5;           // 0..31
    const int bh    = g >> 2;
    const int split = g & 3;
    const int w     = threadIdx.x >> 6;
    const int lane  = threadIdx.x & 63;
    const int quad  = lane >> 4;
    const int li    = lane & 15;
    const int i0    = iblk * 128 + w * 32;
    const int j_lo  = split * 1024;

    const bf16* qrow = qb + (size_t)bh * NPOS * DHEAD;
    const bf16x8 qf0 = *(const bf16x8*)(qrow + (size_t)(i0 + li) * DHEAD + quad * 8);
    const bf16x8 qf1 = *(const bf16x8*)(qrow + (size_t)(i0 + 16 + li) * DHEAD + quad * 8);
    const bf16* kbase  = kb  + (size_t)bh * NPOS * DHEAD;
    const bf16* vtbase = vtb + (size_t)bh * DHEAD * NPOS;

    bf16x8 ones;
    #pragma unroll
    for (int j = 0; j < 8; ++j) ones[j] = (bf16)1.0f;

    f32x4 o00 = {0.f,0.f,0.f,0.f}, o01 = {0.f,0.f,0.f,0.f};
    f32x4 o10 = {0.f,0.f,0.f,0.f}, o11 = {0.f,0.f,0.f,0.f};
    f32x4 l0  = {0.f,0.f,0.f,0.f}, l1  = {0.f,0.f,0.f,0.f};

    __shared__ alignas(16) bf16 Kbuf[2][64][32];   // [buf][j_loc][d], 8 KB
    __shared__ alignas(16) bf16 Vbuf[2][32][64];   // [buf][d][k_slot], 8 KB (slot-swizzled)

    const f32x4 zero = {0.f,0.f,0.f,0.f};

    // staging geometry: each wave stages 16 K-rows (1 KB) + 8 V-rows (1 KB)
    const int krow = w * 16 + (lane >> 2);        // 0..63 (j within tile)
    const int kcol = (lane & 3) * 8;              // d chunk (16 B)
    const int vrow = w * 8 + (lane >> 3);         // 0..31 (d)
    const int vchk = lane & 7;                    // k chunk (16 B)
    const int vslot = vchk ^ (vrow & 7);          // swizzled LDS slot
    const bf16* ksrc = kbase + (size_t)krow * DHEAD + kcol;
    const bf16* vsrc = vtbase + (size_t)vrow * NPOS + vchk * 8;

    bf16x8 kg, vg;

    // prologue: stage tile 0 into buf 0
    kg = *(const bf16x8*)(ksrc + (size_t)j_lo * DHEAD);
    vg = *(const bf16x8*)(vsrc + j_lo);
    *(bf16x8*)&Kbuf[0][krow][kcol]      = kg;
    *(bf16x8*)&Vbuf[0][vrow][vslot * 8] = vg;
    __syncthreads();

    for (int it = 0; it < 16; ++it) {
        const int cur = it & 1;
        const int j0  = j_lo + it * 64;
        // issue next tile's global loads (drain under this iteration's compute)
        if (it < 15) {
            kg = *(const bf16x8*)(ksrc + (size_t)(j0 + 64) * DHEAD);
            vg = *(const bf16x8*)(vsrc + j0 + 64);
        }
        // QK from Kbuf[cur]
        bf16x8 kf[4];
        #pragma unroll
        for (int tt = 0; tt < 4; ++tt)
            kf[tt] = *(const bf16x8*)&Kbuf[cur][16 * tt + li][quad * 8];
        f32x4 s0[4], s1[4];
        #pragma unroll
        for (int tt = 0; tt < 4; ++tt) {
            s0[tt] = __builtin_amdgcn_mfma_f32_16x16x32_bf16(kf[tt], qf0, zero, 0, 0, 0);
            s1[tt] = __builtin_amdgcn_mfma_f32_16x16x32_bf16(kf[tt], qf1, zero, 0, 0, 0);
        }
        // exp in-register -> PV B-fragments directly (k(m) permutation pre-applied to V)
        #pragma unroll
        for (int h2 = 0; h2 < 2; ++h2) {
            B8 pa0, pa1;
            #pragma unroll
            for (int r = 0; r < 4; ++r) {
                pa0.v[r]     = (bf16)__builtin_amdgcn_exp2f(s0[2 * h2][r]);
                pa0.v[4 + r] = (bf16)__builtin_amdgcn_exp2f(s0[2 * h2 + 1][r]);
                pa1.v[r]     = (bf16)__builtin_amdgcn_exp2f(s1[2 * h2][r]);
                pa1.v[4 + r] = (bf16)__builtin_amdgcn_exp2f(s1[2 * h2 + 1][r]);
            }
            const int s0s = (h2 * 4 + quad) ^ (li & 7);   // read swizzle matches write
            bf16x8 v0f = *(const bf16x8*)&Vbuf[cur][li][s0s * 8];
            bf16x8 v1f = *(const bf16x8*)&Vbuf[cur][16 + li][s0s * 8];
            l0  = __builtin_amdgcn_mfma_f32_16x16x32_bf16(ones, pa0.v, l0,  0, 0, 0);
            l1  = __builtin_amdgcn_mfma_f32_16x16x32_bf16(ones, pa1.v, l1,  0, 0, 0);
            o00 = __builtin_amdgcn_mfma_f32_16x16x32_bf16(v0f,  pa0.v, o00, 0, 0, 0);
            o01 = __builtin_amdgcn_mfma_f32_16x16x32_bf16(v1f,  pa0.v, o01, 0, 0, 0);
            o10 = __builtin_amdgcn_mfma_f32_16x16x32_bf16(v0f,  pa1.v, o10, 0, 0, 0);
            o11 = __builtin_amdgcn_mfma_f32_16x16x32_bf16(v1f,  pa1.v, o11, 0, 0, 0);
        }
        // stage next tile into the other buffer (its readers are past the barrier)
        if (it < 15) {
            *(bf16x8*)&Kbuf[cur ^ 1][krow][kcol]      = kg;
            *(bf16x8*)&Vbuf[cur ^ 1][vrow][vslot * 8] = vg;
        }
        __syncthreads();
    }

    const int b = bh >> 2, h = bh & 3;
    {
        const int i = i0 + li;
        bf16* dst = aop + (((size_t)(split * NB + b) * NPOS + i) * HID) + h * DHEAD;
        bf16x4 pk0, pk1;
        #pragma unroll
        for (int r = 0; r < 4; ++r) { pk0[r] = (bf16)o00[r]; pk1[r] = (bf16)o01[r]; }
        *(bf16x4*)(dst + quad * 4)      = pk0;
        *(bf16x4*)(dst + 16 + quad * 4) = pk1;
        if (quad == 0) lpart[((size_t)split * NBH + bh) * NPOS + i] = l0[0];
    }
    {
        const int i = i0 + 16 + li;
        bf16* dst = aop + (((size_t)(split * NB + b) * NPOS + i) * HID) + h * DHEAD;
        bf16x4 pk0, pk1;
        #pragma unroll
        for (int r = 0; r < 4; ++r) { pk0[r] = (bf16)o10[r]; pk1[r] = (bf16)o11[r]; }
        *(bf16x4*)(dst + quad * 4)      = pk0;
        *(bf16x4*)(dst + 16 + quad * 4) = pk1;
        if (quad == 0) lpart[((size_t)split * NBH + bh) * NPOS + i] = l1[0];
    }
}

// ---------------- Kernel 3: proj GEMM — combine ONCE per row ----------------
__global__ __launch_bounds__(256) void proj_kernel(const bf16* __restrict__ aop,
                                                   const float* __restrict__ lpart,
                                                   const bf16* __restrict__ wob,
                                                   const float* __restrict__ bout,
                                                   float* __restrict__ y) {
    const int i0 = blockIdx.x * 16;
    const int b  = blockIdx.y;
    const int t  = threadIdx.x;
    const int w  = t >> 6;
    const int lane = t & 63;
    const int quad = lane >> 4;
    const int li   = lane & 15;

    __shared__ bf16 Bs[16][132];   // [i_loc][c], 4.2 KB

    // staging with combine: thread = (row, 8-channel chunk); each row combined ONCE
    {
        const int row = t >> 4;          // 0..15
        const int cp  = (t & 15) * 8;    // 0..120
        const int gi  = i0 + row;
        const int h   = cp >> 5;

        float lsum = 0.f;
        #pragma unroll
        for (int s = 0; s < NSPLIT; ++s)
            lsum += lpart[((size_t)s * NBH + b * NHEAD + h) * NPOS + gi];
        const float invl = __builtin_amdgcn_rcpf(lsum);

        float vals[8];
        #pragma unroll
        for (int j = 0; j < 8; ++j) vals[j] = 0.f;
        #pragma unroll
        for (int s = 0; s < NSPLIT; ++s) {
            bf16x8 u = *(const bf16x8*)(aop + (((size_t)(s * NB + b) * NPOS + gi) * HID) + cp);
            #pragma unroll
            for (int j = 0; j < 8; ++j) vals[j] += (float)u[j];
        }
        B8 pk;
        #pragma unroll
        for (int j = 0; j < 8; ++j) pk.v[j] = (bf16)(vals[j] * invl);
        *(bf16x4*)&Bs[row][cp]     = pk.h[0];
        *(bf16x4*)&Bs[row][cp + 4] = pk.h[1];
    }
    __syncthreads();

    f32x4 acc[4];
    #pragma unroll
    for (int m = 0; m < 4; ++m) acc[m] = (f32x4){0.f, 0.f, 0.f, 0.f};

    #pragma unroll
    for (int k0 = 0; k0 < HID; k0 += 32) {
        B8 bf;
        bf.h[0] = *(const bf16x4*)&Bs[li][k0 + quad * 8];
        bf.h[1] = *(const bf16x4*)&Bs[li][k0 + quad * 8 + 4];
        #pragma unroll
        for (int m = 0; m < 4; ++m) {
            bf16x8 afrag = *(const bf16x8*)(wob + (size_t)(w * 64 + m * 16 + li) * HID + k0 + quad * 8);
            acc[m] = __builtin_amdgcn_mfma_f32_16x16x32_bf16(afrag, bf.v, acc[m], 0, 0, 0);
        }
    }

    float* yb = y + (size_t)b * CIN * NPOS;
    #pragma unroll
    for (int m = 0; m < 4; ++m) {
        const int oc = w * 64 + m * 16 + quad * 4;
        #pragma unroll
        for (int r = 0; r < 4; ++r)
            yb[(size_t)(oc + r) * NPOS + i0 + li] = acc[m][r] + bout[oc + r];
    }
}

extern "C" void kernel_launch(void* const* d_in, const int* in_sizes, int n_in,
                              void* d_out, int out_size, void* d_ws, size_t ws_size,
                              hipStream_t stream) {
    const float* x    = (const float*)d_in[0];
    const float* wqkv = (const float*)d_in[1];
    const float* wout = (const float*)d_in[2];
    const float* bout = (const float*)d_in[3];
    float* y = (float*)d_out;
    char* ws = (char*)d_ws;

    bf16*  xt  = (bf16*)(ws + XT_OFF);
    bf16*  qb  = (bf16*)(ws + QB_OFF);
    bf16*  kb  = (bf16*)(ws + KB_OFF);
    bf16*  vtb = (bf16*)(ws + VT_OFF);
    bf16*  aop = (bf16*)(ws + AOP_OFF);
    float* lp  = (float*)(ws + LP_OFF);
    bf16*  wb  = (bf16*)(ws + WB_OFF);
    bf16*  wob = (bf16*)(ws + WOB_OFF);

    prep_kernel<<<dim3(64, 5, 2), 256, 0, stream>>>(x, wqkv, wout, xt, wb, wob);
    qkv_kernel<<<dim3(64, 6, 2), 256, 0, stream>>>(xt, wb, qb, kb, vtb);
    fattn_kernel<<<dim3(1024), 256, 0, stream>>>(qb, kb, vtb, aop, lp);
    proj_kernel<<<dim3(256, 2), 256, 0, stream>>>(aop, lp, wob, bout, y);
}